// Round 1
// baseline (390.611 us; speedup 1.0000x reference)
//
#include <hip/hip_runtime.h>

// Problem constants (from reference)
#define NUM_NODES   1200000
#define NUM_FILLER  200000
#define NUM_PHYS    (NUM_NODES - NUM_FILLER)   // 1,000,000
#define NUM_MOVABLE 900000
#define NBX 512
#define NBY 512
#define XL 0.0f
#define YL 0.0f
#define BSX 1.953125f            // 1000/512, exact in fp32
#define BSY 1.953125f
#define PIN_STRETCH 1.4142135623730951f
#define CAP 0.19073486328125f    // BSX*BSY*0.05, exact
#define MAX_RATE 1.5f
#define MIN_RATE (1.0f/1.5f)
#define K 5

// ---------------------------------------------------------------------------
// Phase 1: scatter density-weighted overlap into pin_map (262,144 bins)
// ---------------------------------------------------------------------------
__global__ __launch_bounds__(256) void scatter_pin_map(
    const float* __restrict__ pos,
    const float* __restrict__ nsx,
    const float* __restrict__ nsy,
    const int*   __restrict__ flat,
    float*       __restrict__ pin_map)
{
    int p = blockIdx.x * blockDim.x + threadIdx.x;
    if (p >= NUM_PHYS) return;

    float sx = nsx[p];
    float sy = nsy[p];
    float hx = 0.5f * fmaxf(BSX * PIN_STRETCH, sx);
    float hy = 0.5f * fmaxf(BSY * PIN_STRETCH, sy);
    float cx = pos[p] + 0.5f * sx;
    float cy = pos[NUM_NODES + p] + 0.5f * sy;
    float pw = (float)(flat[p + 1] - flat[p]);
    float density = pw / (4.0f * hx * hy);

    // overlap terms, x axis
    float lox = cx - hx, hix = cx + hx;
    int ilx = (int)floorf((lox - XL) / BSX);
    ilx = min(max(ilx, 0), NBX - 1);
    float ovx[K]; int idx_x[K];
    #pragma unroll
    for (int k = 0; k < K; ++k) {
        int idx = ilx + k;
        bool valid = idx < NBX;
        int idc = min(idx, NBX - 1);
        float b_lo = XL + (float)idc * BSX;
        float ov = fmaxf(fminf(hix, b_lo + BSX) - fmaxf(lox, b_lo), 0.0f);
        ovx[k] = valid ? ov : 0.0f;
        idx_x[k] = idc;
    }
    // overlap terms, y axis
    float loy = cy - hy, hiy = cy + hy;
    int ily = (int)floorf((loy - YL) / BSY);
    ily = min(max(ily, 0), NBY - 1);
    float ovy[K]; int idx_y[K];
    #pragma unroll
    for (int k = 0; k < K; ++k) {
        int idx = ily + k;
        bool valid = idx < NBY;
        int idc = min(idx, NBY - 1);
        float b_lo = YL + (float)idc * BSY;
        float ov = fmaxf(fminf(hiy, b_lo + BSY) - fmaxf(loy, b_lo), 0.0f);
        ovy[k] = valid ? ov : 0.0f;
        idx_y[k] = idc;
    }

    #pragma unroll
    for (int i = 0; i < K; ++i) {
        if (ovx[i] == 0.0f) continue;
        int rowbase = idx_x[i] * NBY;
        #pragma unroll
        for (int j = 0; j < K; ++j) {
            float c = ovx[i] * ovy[j] * density;
            if (c != 0.0f) {
                atomicAdd(&pin_map[rowbase + idx_y[j]], c);
            }
        }
    }
}

// ---------------------------------------------------------------------------
// Phase 2: gather clipped utilization for movable nodes
// ---------------------------------------------------------------------------
__global__ __launch_bounds__(256) void gather_pin_area(
    const float* __restrict__ pos,
    const float* __restrict__ nsx,
    const float* __restrict__ nsy,
    const float* __restrict__ pin_map,
    float*       __restrict__ out)
{
    int m = blockIdx.x * blockDim.x + threadIdx.x;
    if (m >= NUM_MOVABLE) return;

    float xlo = pos[m];
    float xhi = xlo + nsx[m];
    float ylo = pos[NUM_NODES + m];
    float yhi = ylo + nsy[m];

    int ilx = (int)floorf((xlo - XL) / BSX);
    ilx = min(max(ilx, 0), NBX - 1);
    float wx[K]; int jx[K];
    #pragma unroll
    for (int k = 0; k < K; ++k) {
        int idx = ilx + k;
        bool valid = idx < NBX;
        int idc = min(idx, NBX - 1);
        float b_lo = XL + (float)idc * BSX;
        float ov = fmaxf(fminf(xhi, b_lo + BSX) - fmaxf(xlo, b_lo), 0.0f);
        wx[k] = valid ? ov : 0.0f;
        jx[k] = idc;
    }
    int ily = (int)floorf((ylo - YL) / BSY);
    ily = min(max(ily, 0), NBY - 1);
    float wy[K]; int jy[K];
    #pragma unroll
    for (int k = 0; k < K; ++k) {
        int idx = ily + k;
        bool valid = idx < NBY;
        int idc = min(idx, NBY - 1);
        float b_lo = YL + (float)idc * BSY;
        float ov = fmaxf(fminf(yhi, b_lo + BSY) - fmaxf(ylo, b_lo), 0.0f);
        wy[k] = valid ? ov : 0.0f;
        jy[k] = idc;
    }

    float acc = 0.0f;
    #pragma unroll
    for (int i = 0; i < K; ++i) {
        if (wx[i] == 0.0f) continue;
        int rowbase = jx[i] * NBY;
        #pragma unroll
        for (int j = 0; j < K; ++j) {
            if (wy[j] == 0.0f) continue;
            float u = pin_map[rowbase + jy[j]] / CAP;
            u = fminf(fmaxf(u, MIN_RATE), MAX_RATE);
            acc += wx[i] * wy[j] * u;
        }
    }
    out[m] = acc;
}

extern "C" void kernel_launch(void* const* d_in, const int* in_sizes, int n_in,
                              void* d_out, int out_size, void* d_ws, size_t ws_size,
                              hipStream_t stream) {
    const float* pos  = (const float*)d_in[0];
    const float* nsx  = (const float*)d_in[1];
    const float* nsy  = (const float*)d_in[2];
    const int*   flat = (const int*)d_in[3];
    float* out = (float*)d_out;
    float* pin_map = (float*)d_ws;   // NBX*NBY floats = 1 MB

    hipMemsetAsync(pin_map, 0, NBX * NBY * sizeof(float), stream);

    dim3 blk(256);
    dim3 grd1((NUM_PHYS + 255) / 256);
    scatter_pin_map<<<grd1, blk, 0, stream>>>(pos, nsx, nsy, flat, pin_map);

    dim3 grd2((NUM_MOVABLE + 255) / 256);
    gather_pin_area<<<grd2, blk, 0, stream>>>(pos, nsx, nsy, pin_map, out);
}